// Round 3
// baseline (253.470 us; speedup 1.0000x reference)
//
#include <hip/hip_runtime.h>
#include <math.h>

#define BS 2048   // B*S tokens
#define H  1024
#define E  8
#define F  512
#define BK 32
#define LDK 40    // LDS A row stride in u16: 80 B = 16B-aligned, <=2-way bank conflicts

typedef __attribute__((ext_vector_type(8))) short bf16x8;
typedef __attribute__((ext_vector_type(4))) float f32x4;
typedef unsigned short u16;
typedef unsigned int u32;

__device__ inline u16 f2bf(float f) {
    u32 u = __float_as_uint(f);
    return (u16)((u + 0x7fffu + ((u >> 16) & 1u)) >> 16);
}

// ws layout (bytes):
//        0: counters: valid[8], mismatch[8], gcount[8]
//     4096: sel      int2[BS]
//    20480: wsel     float2[BS]
//    36864: tok_list int[E*BS]
//   102400: w_list   float[E*BS]
//   167936: x_bf     u16[BS*H]            (4 MB)
//  4362240: gup_t    u16[E*1024*1024]     (16 MB)  [e][f-col][h-k] transposed bf16
// 21139456: down_t   u16[E*1024*512]      (8 MB)   [e][h-col][f-k] transposed bf16
// 29528064: act      u16[4096*F]          (4 MB)   w-scaled silu(g)*u, bf16

__global__ __launch_bounds__(256) void zero_kernel(float* __restrict__ out, int* __restrict__ counters) {
    int idx = blockIdx.x * 256 + threadIdx.x;
    if (idx < 24) counters[idx] = 0;
    float4 z = make_float4(0.f, 0.f, 0.f, 0.f);
    size_t n4 = (size_t)BS * H / 4;
    for (size_t i = idx; i < n4; i += (size_t)gridDim.x * 256) ((float4*)out)[i] = z;
}

// gup[e][k=h][n=f2] fp32 -> gup_t[e][n][k] bf16, 64x64 LDS tile transpose
__global__ __launch_bounds__(256) void transpose_gup_kernel(const float* __restrict__ g, u16* __restrict__ gt) {
    int e = blockIdx.z, k0 = blockIdx.x * 64, n0 = blockIdx.y * 64;
    __shared__ float t[64][68];
    int tid = threadIdx.x;
    int r = tid >> 2, c4 = tid & 3;
    const float* src = g + (size_t)e * 1048576 + (size_t)(k0 + r) * 1024 + n0 + c4 * 16;
#pragma unroll
    for (int i = 0; i < 4; i++) {
        float4 v = *(const float4*)(src + i * 4);
        *(float4*)&t[r][c4 * 16 + i * 4] = v;
    }
    __syncthreads();
    int nr = r, kc = c4;
    u16 o[16];
#pragma unroll
    for (int m = 0; m < 16; m++) o[m] = f2bf(t[kc * 16 + m][nr]);
    u16* dst = gt + (size_t)e * 1048576 + (size_t)(n0 + nr) * 1024 + k0 + kc * 16;
    uint4 q0, q1;
    q0.x = (u32)o[0] | ((u32)o[1] << 16);  q0.y = (u32)o[2] | ((u32)o[3] << 16);
    q0.z = (u32)o[4] | ((u32)o[5] << 16);  q0.w = (u32)o[6] | ((u32)o[7] << 16);
    q1.x = (u32)o[8] | ((u32)o[9] << 16);  q1.y = (u32)o[10] | ((u32)o[11] << 16);
    q1.z = (u32)o[12] | ((u32)o[13] << 16); q1.w = (u32)o[14] | ((u32)o[15] << 16);
    *(uint4*)dst = q0;
    *(uint4*)(dst + 8) = q1;
}

// down[e][k=f][n=h] fp32 -> down_t[e][n][k] bf16
__global__ __launch_bounds__(256) void transpose_down_kernel(const float* __restrict__ d, u16* __restrict__ dt) {
    int e = blockIdx.z, k0 = blockIdx.x * 64, n0 = blockIdx.y * 64;
    __shared__ float t[64][68];
    int tid = threadIdx.x;
    int r = tid >> 2, c4 = tid & 3;
    const float* src = d + (size_t)e * 524288 + (size_t)(k0 + r) * 1024 + n0 + c4 * 16;
#pragma unroll
    for (int i = 0; i < 4; i++) {
        float4 v = *(const float4*)(src + i * 4);
        *(float4*)&t[r][c4 * 16 + i * 4] = v;
    }
    __syncthreads();
    int nr = r, kc = c4;
    u16 o[16];
#pragma unroll
    for (int m = 0; m < 16; m++) o[m] = f2bf(t[kc * 16 + m][nr]);
    u16* dst = dt + (size_t)e * 524288 + (size_t)(n0 + nr) * 512 + k0 + kc * 16;
    uint4 q0, q1;
    q0.x = (u32)o[0] | ((u32)o[1] << 16);  q0.y = (u32)o[2] | ((u32)o[3] << 16);
    q0.z = (u32)o[4] | ((u32)o[5] << 16);  q0.w = (u32)o[6] | ((u32)o[7] << 16);
    q1.x = (u32)o[8] | ((u32)o[9] << 16);  q1.y = (u32)o[10] | ((u32)o[11] << 16);
    q1.z = (u32)o[12] | ((u32)o[13] << 16); q1.w = (u32)o[14] | ((u32)o[15] << 16);
    *(uint4*)dst = q0;
    *(uint4*)(dst + 8) = q1;
}

// router + x->bf16 conversion fused. One wave per token, no LDS (gate_w is L1/L2-hot).
__global__ __launch_bounds__(256) void router_kernel(
    const float* __restrict__ x, const float* __restrict__ gate_w,
    const int* __restrict__ tok_mod, const int* __restrict__ exp_mod,
    int* __restrict__ counters, int2* __restrict__ sel_out, float2* __restrict__ w_out,
    u16* __restrict__ xb)
{
    int tid = threadIdx.x;
    int wv = tid >> 6, lane = tid & 63;
    int token = blockIdx.x * 4 + wv;    // grid = BS/4 = 512
    const float4* xr4 = (const float4*)(x + (size_t)token * H);
    const float4* gw4 = (const float4*)gate_w;
    float acc[E];
#pragma unroll
    for (int e = 0; e < E; e++) acc[e] = 0.f;
#pragma unroll
    for (int i = 0; i < 4; i++) {
        int idx = lane + 64 * i;
        float4 xv = xr4[idx];
        ushort4 pk;
        pk.x = f2bf(xv.x); pk.y = f2bf(xv.y); pk.z = f2bf(xv.z); pk.w = f2bf(xv.w);
        *(ushort4*)(xb + (size_t)token * H + idx * 4) = pk;
#pragma unroll
        for (int e = 0; e < E; e++) {
            float4 g = gw4[e * 256 + idx];
            acc[e] += xv.x * g.x + xv.y * g.y + xv.z * g.z + xv.w * g.w;
        }
    }
#pragma unroll
    for (int e = 0; e < E; e++) {
#pragma unroll
        for (int off = 32; off > 0; off >>= 1) acc[e] += __shfl_down(acc[e], off, 64);
    }
    if (lane == 0) {
        float m = acc[0];
#pragma unroll
        for (int e = 1; e < E; e++) m = fmaxf(m, acc[e]);
        float p[E]; float s = 0.f;
#pragma unroll
        for (int e = 0; e < E; e++) { p[e] = expf(acc[e] - m); s += p[e]; }
        float inv = 1.f / s;
#pragma unroll
        for (int e = 0; e < E; e++) p[e] *= inv;
        int i0 = 0; float p0 = p[0];
#pragma unroll
        for (int e = 1; e < E; e++) if (p[e] > p0) { p0 = p[e]; i0 = e; }
        int i1 = -1; float p1 = -1.f;
#pragma unroll
        for (int e = 0; e < E; e++) if (e != i0 && p[e] > p1) { p1 = p[e]; i1 = e; }
        float rs = 1.f / (p0 + p1);
        float w0 = p0 * rs, w1 = p1 * rs;
        int tm = tok_mod[token];
        int em0 = exp_mod[i0], em1 = exp_mod[i1];
        bool v0 = (tm != 0) && (em0 != 0);
        bool v1 = (tm != 0) && (em1 != 0);
        bool mm0 = v0 && (tm * em0 == -1);
        bool mm1 = v1 && (tm * em1 == -1);
        if (v0)  atomicAdd(&counters[i0], 1);
        if (v1)  atomicAdd(&counters[i1], 1);
        if (mm0) atomicAdd(&counters[8 + i0], 1);
        if (mm1) atomicAdd(&counters[8 + i1], 1);
        sel_out[token] = make_int2(i0, i1);
        w_out[token] = make_float2(w0, w1);
    }
}

__global__ __launch_bounds__(256) void finalize_kernel(
    const int* __restrict__ exp_mod, int* __restrict__ counters,
    const int2* __restrict__ sel_in, const float2* __restrict__ w_in,
    int* __restrict__ tok_list, float* __restrict__ w_list)
{
    int t = blockIdx.x * 256 + threadIdx.x;
    if (t >= BS) return;
    bool skip[E];
#pragma unroll
    for (int e = 0; e < E; e++) {
        int vc = counters[e], mc = counters[8 + e];
        skip[e] = (vc > 0) && (mc == vc) && (exp_mod[e] != 0);
    }
    int2 sel = sel_in[t];
    float2 w = w_in[t];
    float w0 = skip[sel.x] ? 0.f : w.x;
    float w1 = skip[sel.y] ? 0.f : w.y;
    float s = w0 + w1;
    if (s > 0.f) { float inv = 1.f / fmaxf(s, 1e-9f); w0 *= inv; w1 *= inv; }
    if (w0 > 0.f) {
        int pos = atomicAdd(&counters[16 + sel.x], 1);
        tok_list[sel.x * BS + pos] = t; w_list[sel.x * BS + pos] = w0;
    }
    if (w1 > 0.f) {
        int pos = atomicAdd(&counters[16 + sel.y], 1);
        tok_list[sel.y * BS + pos] = t; w_list[sel.y * BS + pos] = w1;
    }
}

// gu MFMA v3: block tile M=64, N=64g+64u. 4 waves 2x2 (mh: 32 rows, nh: 32 cols).
// A double-buffered in LDS (single barrier/kstep); B direct global->VGPR (L2-hot).
__global__ __launch_bounds__(256) void gu_mfma_kernel(
    const u16* __restrict__ xb, const u16* __restrict__ gup_t,
    const int* __restrict__ counters, const int* __restrict__ tok_list,
    const float* __restrict__ w_list, u16* __restrict__ act)
{
    int e = blockIdx.z;
    int n = counters[16 + e];
    int t0 = blockIdx.y * 64;
    if (t0 >= n) return;
    int f0 = blockIdx.x * 64;
    int base = 0;
#pragma unroll
    for (int i = 0; i < E; i++) if (i < e) base += counters[16 + i];

    __shared__ __align__(16) u16 Al[2][64 * LDK];   // 2 x 5120 B

    int tid = threadIdx.x;
    int wv = tid >> 6, lane = tid & 63;
    int l16 = lane & 15, quad = lane >> 4;
    int mh = wv & 1, nh = wv >> 1;

    // A staging: wave wv stages rows [wv*16, wv*16+16), lane: row=lane>>2, kchunk=lane&3
    int srow = wv * 16 + (lane >> 2);
    int tokA = tok_list[e * BS + min(t0 + srow, n - 1)];
    const u16* aptr = xb + (size_t)tokA * H + (lane & 3) * 8;
    u16* awr = &Al[0][srow * LDK + (lane & 3) * 8];

    // B fragment pointers (direct global reads, [n-col][k] layout)
    const u16* gb = gup_t + ((size_t)e << 20);
    const u16* bgp0 = gb + (size_t)(f0 + nh * 32 + l16) * H + quad * 8;
    const u16* bgp1 = bgp0 + (size_t)16 * H;
    const u16* bup0 = gb + (size_t)(512 + f0 + nh * 32 + l16) * H + quad * 8;
    const u16* bup1 = bup0 + (size_t)16 * H;

    f32x4 accg[2][2], accu[2][2];
#pragma unroll
    for (int i = 0; i < 2; i++)
#pragma unroll
        for (int j = 0; j < 2; j++) {
            accg[i][j] = (f32x4){0.f, 0.f, 0.f, 0.f};
            accu[i][j] = (f32x4){0.f, 0.f, 0.f, 0.f};
        }

    uint4 va = *(const uint4*)aptr;
    int p = 0;
    for (int k0 = 0; k0 < H; k0 += BK) {
        *(uint4*)(awr + p * 64 * LDK) = va;
        if (k0 + BK < H) va = *(const uint4*)(aptr + k0 + BK);
        bf16x8 bg0 = *(const bf16x8*)(bgp0 + k0);
        bf16x8 bg1 = *(const bf16x8*)(bgp1 + k0);
        bf16x8 bu0 = *(const bf16x8*)(bup0 + k0);
        bf16x8 bu1 = *(const bf16x8*)(bup1 + k0);
        __syncthreads();
        bf16x8 a0 = *(const bf16x8*)&Al[p][(mh * 32 + l16) * LDK + quad * 8];
        bf16x8 a1 = *(const bf16x8*)&Al[p][(mh * 32 + 16 + l16) * LDK + quad * 8];
        accg[0][0] = __builtin_amdgcn_mfma_f32_16x16x32_bf16(a0, bg0, accg[0][0], 0, 0, 0);
        accg[0][1] = __builtin_amdgcn_mfma_f32_16x16x32_bf16(a0, bg1, accg[0][1], 0, 0, 0);
        accu[0][0] = __builtin_amdgcn_mfma_f32_16x16x32_bf16(a0, bu0, accu[0][0], 0, 0, 0);
        accu[0][1] = __builtin_amdgcn_mfma_f32_16x16x32_bf16(a0, bu1, accu[0][1], 0, 0, 0);
        accg[1][0] = __builtin_amdgcn_mfma_f32_16x16x32_bf16(a1, bg0, accg[1][0], 0, 0, 0);
        accg[1][1] = __builtin_amdgcn_mfma_f32_16x16x32_bf16(a1, bg1, accg[1][1], 0, 0, 0);
        accu[1][0] = __builtin_amdgcn_mfma_f32_16x16x32_bf16(a1, bu0, accu[1][0], 0, 0, 0);
        accu[1][1] = __builtin_amdgcn_mfma_f32_16x16x32_bf16(a1, bu1, accu[1][1], 0, 0, 0);
        p ^= 1;
    }
    // epilogue: C layout col=lane&15, row=quad*4+reg
#pragma unroll
    for (int i = 0; i < 2; i++)
#pragma unroll
        for (int r = 0; r < 4; r++) {
            int R = t0 + mh * 32 + i * 16 + quad * 4 + r;
            if (R < n) {
                float w = w_list[e * BS + R];
                size_t rowoff = (size_t)(base + R) * F + f0 + nh * 32 + l16;
#pragma unroll
                for (int j = 0; j < 2; j++) {
                    float g = accg[i][j][r], u = accu[i][j][r];
                    float v = (g / (1.f + expf(-g))) * u * w;
                    act[rowoff + j * 16] = f2bf(v);
                }
            }
        }
}

// down MFMA v3: block tile M=64, N=128. Waves 2x2 (mh: 32 rows, nh: 64 cols).
__global__ __launch_bounds__(256) void down_mfma_kernel(
    const u16* __restrict__ act, const u16* __restrict__ down_t,
    const int* __restrict__ counters, const int* __restrict__ tok_list,
    float* __restrict__ out)
{
    int e = blockIdx.z;
    int n = counters[16 + e];
    int t0 = blockIdx.y * 64;
    if (t0 >= n) return;
    int h0 = blockIdx.x * 128;
    int base = 0;
#pragma unroll
    for (int i = 0; i < E; i++) if (i < e) base += counters[16 + i];

    __shared__ __align__(16) u16 Al[2][64 * LDK];

    int tid = threadIdx.x;
    int wv = tid >> 6, lane = tid & 63;
    int l16 = lane & 15, quad = lane >> 4;
    int mh = wv & 1, nh = wv >> 1;

    int srow = wv * 16 + (lane >> 2);
    int arow = min(t0 + srow, n - 1);
    const u16* aptr = act + (size_t)(base + arow) * F + (lane & 3) * 8;
    u16* awr = &Al[0][srow * LDK + (lane & 3) * 8];

    const u16* db = down_t + ((size_t)e << 19);
    const u16* bp0 = db + (size_t)(h0 + nh * 64 + l16) * F + quad * 8;
    const u16* bp1 = bp0 + (size_t)16 * F;
    const u16* bp2 = bp0 + (size_t)32 * F;
    const u16* bp3 = bp0 + (size_t)48 * F;

    f32x4 acc[2][4];
#pragma unroll
    for (int i = 0; i < 2; i++)
#pragma unroll
        for (int j = 0; j < 4; j++) acc[i][j] = (f32x4){0.f, 0.f, 0.f, 0.f};

    uint4 va = *(const uint4*)aptr;
    int p = 0;
    for (int k0 = 0; k0 < F; k0 += BK) {
        *(uint4*)(awr + p * 64 * LDK) = va;
        if (k0 + BK < F) va = *(const uint4*)(aptr + k0 + BK);
        bf16x8 b0 = *(const bf16x8*)(bp0 + k0);
        bf16x8 b1 = *(const bf16x8*)(bp1 + k0);
        bf16x8 b2 = *(const bf16x8*)(bp2 + k0);
        bf16x8 b3 = *(const bf16x8*)(bp3 + k0);
        __syncthreads();
        bf16x8 a0 = *(const bf16x8*)&Al[p][(mh * 32 + l16) * LDK + quad * 8];
        bf16x8 a1 = *(const bf16x8*)&Al[p][(mh * 32 + 16 + l16) * LDK + quad * 8];
        acc[0][0] = __builtin_amdgcn_mfma_f32_16x16x32_bf16(a0, b0, acc[0][0], 0, 0, 0);
        acc[0][1] = __builtin_amdgcn_mfma_f32_16x16x32_bf16(a0, b1, acc[0][1], 0, 0, 0);
        acc[0][2] = __builtin_amdgcn_mfma_f32_16x16x32_bf16(a0, b2, acc[0][2], 0, 0, 0);
        acc[0][3] = __builtin_amdgcn_mfma_f32_16x16x32_bf16(a0, b3, acc[0][3], 0, 0, 0);
        acc[1][0] = __builtin_amdgcn_mfma_f32_16x16x32_bf16(a1, b0, acc[1][0], 0, 0, 0);
        acc[1][1] = __builtin_amdgcn_mfma_f32_16x16x32_bf16(a1, b1, acc[1][1], 0, 0, 0);
        acc[1][2] = __builtin_amdgcn_mfma_f32_16x16x32_bf16(a1, b2, acc[1][2], 0, 0, 0);
        acc[1][3] = __builtin_amdgcn_mfma_f32_16x16x32_bf16(a1, b3, acc[1][3], 0, 0, 0);
        p ^= 1;
    }
#pragma unroll
    for (int i = 0; i < 2; i++)
#pragma unroll
        for (int r = 0; r < 4; r++) {
            int R = t0 + mh * 32 + i * 16 + quad * 4 + r;
            if (R < n) {
                int tok = tok_list[e * BS + R];
                float* orow = out + (size_t)tok * H + h0 + nh * 64 + l16;
#pragma unroll
                for (int j = 0; j < 4; j++)
                    atomicAdd(&orow[j * 16], acc[i][j][r]);
            }
        }
}

extern "C" void kernel_launch(void* const* d_in, const int* in_sizes, int n_in,
                              void* d_out, int out_size, void* d_ws, size_t ws_size,
                              hipStream_t stream)
{
    const float* x       = (const float*)d_in[0];
    const float* gate_w  = (const float*)d_in[1];
    const float* gup     = (const float*)d_in[2];
    const float* down    = (const float*)d_in[3];
    const int*   tok_mod = (const int*)d_in[4];
    const int*   exp_mod = (const int*)d_in[5];
    float* out = (float*)d_out;

    char* ws = (char*)d_ws;
    int*    counters = (int*)ws;
    int2*   sel      = (int2*)(ws + 4096);
    float2* wsel     = (float2*)(ws + 20480);
    int*    tok_list = (int*)(ws + 36864);
    float*  w_list   = (float*)(ws + 102400);
    u16*    x_bf     = (u16*)(ws + 167936);
    u16*    gup_t    = (u16*)(ws + 4362240);
    u16*    down_t   = (u16*)(ws + 21139456);
    u16*    act      = (u16*)(ws + 29528064);

    zero_kernel<<<2048, 256, 0, stream>>>(out, counters);
    transpose_gup_kernel<<<dim3(16, 16, E), 256, 0, stream>>>(gup, gup_t);
    transpose_down_kernel<<<dim3(8, 16, E), 256, 0, stream>>>(down, down_t);
    router_kernel<<<BS / 4, 256, 0, stream>>>(x, gate_w, tok_mod, exp_mod, counters, sel, wsel, x_bf);
    finalize_kernel<<<BS / 256, 256, 0, stream>>>(exp_mod, counters, sel, wsel, tok_list, w_list);
    gu_mfma_kernel<<<dim3(8, 32, E), 256, 0, stream>>>(x_bf, gup_t, counters, tok_list, w_list, act);
    down_mfma_kernel<<<dim3(8, 32, E), 256, 0, stream>>>(act, down_t, counters, tok_list, out);
}

// Round 4
// 196.868 us; speedup vs baseline: 1.2875x; 1.2875x over previous
//
#include <hip/hip_runtime.h>
#include <math.h>

#define BS 2048   // B*S tokens
#define H  1024
#define E  8
#define F  512

typedef __attribute__((ext_vector_type(8))) short bf16x8;
typedef __attribute__((ext_vector_type(4))) float f32x4;
typedef unsigned short u16;
typedef unsigned int u32;

__device__ inline u16 f2bf(float f) {
    u32 u = __float_as_uint(f);
    return (u16)((u + 0x7fffu + ((u >> 16) & 1u)) >> 16);
}

// async 16B global->LDS. LDS dst is wave-uniform base + lane*16; our lane->lds
// mapping is constructed to be exactly that. Swizzle lives on the GLOBAL side.
__device__ __forceinline__ void async_cp16(const u16* g, u16* l) {
    __builtin_amdgcn_global_load_lds(
        (const __attribute__((address_space(1))) void*)g,
        (__attribute__((address_space(3))) void*)l, 16, 0, 0);
}

// ws layout (bytes):
//        0: counters: valid[8], mismatch[8], gcount[8]
//     4096: sel      int2[BS]
//    20480: wsel     float2[BS]
//    36864: tok_list int[E*BS]
//   102400: w_list   float[E*BS]
//   167936: x_bf     u16[BS*H]            (4 MB)
//  4362240: gup_t    u16[E*1024*1024]     (16 MB)  [e][f-col][h-k] transposed bf16
// 21139456: down_t   u16[E*1024*512]      (8 MB)   [e][h-col][f-k] transposed bf16
// 29528064: act      u16[4096*F]          (4 MB)   w-scaled silu(g)*u, bf16

__global__ __launch_bounds__(256) void zero_kernel(float* __restrict__ out, int* __restrict__ counters) {
    int idx = blockIdx.x * 256 + threadIdx.x;
    if (idx < 24) counters[idx] = 0;
    float4 z = make_float4(0.f, 0.f, 0.f, 0.f);
    size_t n4 = (size_t)BS * H / 4;
    for (size_t i = idx; i < n4; i += (size_t)gridDim.x * 256) ((float4*)out)[i] = z;
}

// gup[e][k=h][n=f2] fp32 -> gup_t[e][n][k] bf16, 64x64 LDS tile transpose
__global__ __launch_bounds__(256) void transpose_gup_kernel(const float* __restrict__ g, u16* __restrict__ gt) {
    int e = blockIdx.z, k0 = blockIdx.x * 64, n0 = blockIdx.y * 64;
    __shared__ float t[64][68];
    int tid = threadIdx.x;
    int r = tid >> 2, c4 = tid & 3;
    const float* src = g + (size_t)e * 1048576 + (size_t)(k0 + r) * 1024 + n0 + c4 * 16;
#pragma unroll
    for (int i = 0; i < 4; i++) {
        float4 v = *(const float4*)(src + i * 4);
        *(float4*)&t[r][c4 * 16 + i * 4] = v;
    }
    __syncthreads();
    int nr = r, kc = c4;
    u16 o[16];
#pragma unroll
    for (int m = 0; m < 16; m++) o[m] = f2bf(t[kc * 16 + m][nr]);
    u16* dst = gt + (size_t)e * 1048576 + (size_t)(n0 + nr) * 1024 + k0 + kc * 16;
    uint4 q0, q1;
    q0.x = (u32)o[0] | ((u32)o[1] << 16);  q0.y = (u32)o[2] | ((u32)o[3] << 16);
    q0.z = (u32)o[4] | ((u32)o[5] << 16);  q0.w = (u32)o[6] | ((u32)o[7] << 16);
    q1.x = (u32)o[8] | ((u32)o[9] << 16);  q1.y = (u32)o[10] | ((u32)o[11] << 16);
    q1.z = (u32)o[12] | ((u32)o[13] << 16); q1.w = (u32)o[14] | ((u32)o[15] << 16);
    *(uint4*)dst = q0;
    *(uint4*)(dst + 8) = q1;
}

// down[e][k=f][n=h] fp32 -> down_t[e][n][k] bf16
__global__ __launch_bounds__(256) void transpose_down_kernel(const float* __restrict__ d, u16* __restrict__ dt) {
    int e = blockIdx.z, k0 = blockIdx.x * 64, n0 = blockIdx.y * 64;
    __shared__ float t[64][68];
    int tid = threadIdx.x;
    int r = tid >> 2, c4 = tid & 3;
    const float* src = d + (size_t)e * 524288 + (size_t)(k0 + r) * 1024 + n0 + c4 * 16;
#pragma unroll
    for (int i = 0; i < 4; i++) {
        float4 v = *(const float4*)(src + i * 4);
        *(float4*)&t[r][c4 * 16 + i * 4] = v;
    }
    __syncthreads();
    int nr = r, kc = c4;
    u16 o[16];
#pragma unroll
    for (int m = 0; m < 16; m++) o[m] = f2bf(t[kc * 16 + m][nr]);
    u16* dst = dt + (size_t)e * 524288 + (size_t)(n0 + nr) * 512 + k0 + kc * 16;
    uint4 q0, q1;
    q0.x = (u32)o[0] | ((u32)o[1] << 16);  q0.y = (u32)o[2] | ((u32)o[3] << 16);
    q0.z = (u32)o[4] | ((u32)o[5] << 16);  q0.w = (u32)o[6] | ((u32)o[7] << 16);
    q1.x = (u32)o[8] | ((u32)o[9] << 16);  q1.y = (u32)o[10] | ((u32)o[11] << 16);
    q1.z = (u32)o[12] | ((u32)o[13] << 16); q1.w = (u32)o[14] | ((u32)o[15] << 16);
    *(uint4*)dst = q0;
    *(uint4*)(dst + 8) = q1;
}

// router + x->bf16 conversion fused. One wave per token.
__global__ __launch_bounds__(256) void router_kernel(
    const float* __restrict__ x, const float* __restrict__ gate_w,
    const int* __restrict__ tok_mod, const int* __restrict__ exp_mod,
    int* __restrict__ counters, int2* __restrict__ sel_out, float2* __restrict__ w_out,
    u16* __restrict__ xb)
{
    int tid = threadIdx.x;
    int wv = tid >> 6, lane = tid & 63;
    int token = blockIdx.x * 4 + wv;    // grid = BS/4 = 512
    const float4* xr4 = (const float4*)(x + (size_t)token * H);
    const float4* gw4 = (const float4*)gate_w;
    float acc[E];
#pragma unroll
    for (int e = 0; e < E; e++) acc[e] = 0.f;
#pragma unroll
    for (int i = 0; i < 4; i++) {
        int idx = lane + 64 * i;
        float4 xv = xr4[idx];
        ushort4 pk;
        pk.x = f2bf(xv.x); pk.y = f2bf(xv.y); pk.z = f2bf(xv.z); pk.w = f2bf(xv.w);
        *(ushort4*)(xb + (size_t)token * H + idx * 4) = pk;
#pragma unroll
        for (int e = 0; e < E; e++) {
            float4 g = gw4[e * 256 + idx];
            acc[e] += xv.x * g.x + xv.y * g.y + xv.z * g.z + xv.w * g.w;
        }
    }
#pragma unroll
    for (int e = 0; e < E; e++) {
#pragma unroll
        for (int off = 32; off > 0; off >>= 1) acc[e] += __shfl_down(acc[e], off, 64);
    }
    if (lane == 0) {
        float m = acc[0];
#pragma unroll
        for (int e = 1; e < E; e++) m = fmaxf(m, acc[e]);
        float p[E]; float s = 0.f;
#pragma unroll
        for (int e = 0; e < E; e++) { p[e] = expf(acc[e] - m); s += p[e]; }
        float inv = 1.f / s;
#pragma unroll
        for (int e = 0; e < E; e++) p[e] *= inv;
        int i0 = 0; float p0 = p[0];
#pragma unroll
        for (int e = 1; e < E; e++) if (p[e] > p0) { p0 = p[e]; i0 = e; }
        int i1 = -1; float p1 = -1.f;
#pragma unroll
        for (int e = 0; e < E; e++) if (e != i0 && p[e] > p1) { p1 = p[e]; i1 = e; }
        float rs = 1.f / (p0 + p1);
        float w0 = p0 * rs, w1 = p1 * rs;
        int tm = tok_mod[token];
        int em0 = exp_mod[i0], em1 = exp_mod[i1];
        bool v0 = (tm != 0) && (em0 != 0);
        bool v1 = (tm != 0) && (em1 != 0);
        bool mm0 = v0 && (tm * em0 == -1);
        bool mm1 = v1 && (tm * em1 == -1);
        if (v0)  atomicAdd(&counters[i0], 1);
        if (v1)  atomicAdd(&counters[i1], 1);
        if (mm0) atomicAdd(&counters[8 + i0], 1);
        if (mm1) atomicAdd(&counters[8 + i1], 1);
        sel_out[token] = make_int2(i0, i1);
        w_out[token] = make_float2(w0, w1);
    }
}

__global__ __launch_bounds__(256) void finalize_kernel(
    const int* __restrict__ exp_mod, int* __restrict__ counters,
    const int2* __restrict__ sel_in, const float2* __restrict__ w_in,
    int* __restrict__ tok_list, float* __restrict__ w_list)
{
    int t = blockIdx.x * 256 + threadIdx.x;
    if (t >= BS) return;
    bool skip[E];
#pragma unroll
    for (int e = 0; e < E; e++) {
        int vc = counters[e], mc = counters[8 + e];
        skip[e] = (vc > 0) && (mc == vc) && (exp_mod[e] != 0);
    }
    int2 sel = sel_in[t];
    float2 w = w_in[t];
    float w0 = skip[sel.x] ? 0.f : w.x;
    float w1 = skip[sel.y] ? 0.f : w.y;
    float s = w0 + w1;
    if (s > 0.f) { float inv = 1.f / fmaxf(s, 1e-9f); w0 *= inv; w1 *= inv; }
    if (w0 > 0.f) {
        int pos = atomicAdd(&counters[16 + sel.x], 1);
        tok_list[sel.x * BS + pos] = t; w_list[sel.x * BS + pos] = w0;
    }
    if (w1 > 0.f) {
        int pos = atomicAdd(&counters[16 + sel.y], 1);
        tok_list[sel.y * BS + pos] = t; w_list[sel.y * BS + pos] = w1;
    }
}

// gu MFMA v4: tile M=64, N=128 (g64|u64), BK=64 macro-steps.
// A+B staged via global_load_lds(16B), XOR-swizzled BK=64 rows (128B), no pad.
// Waves 2x2: wm = 32 rows, wn = 32 g-cols + paired 32 u-cols (silu pairing intra-lane).
__global__ __launch_bounds__(256) void gu_mfma_kernel(
    const u16* __restrict__ xb, const u16* __restrict__ gup_t,
    const int* __restrict__ counters, const int* __restrict__ tok_list,
    const float* __restrict__ w_list, u16* __restrict__ act)
{
    int e = blockIdx.z;
    int n = counters[16 + e];
    int t0 = blockIdx.y * 64;
    if (t0 >= n) return;
    int f0 = blockIdx.x * 64;
    int base = 0;
#pragma unroll
    for (int i = 0; i < E; i++) if (i < e) base += counters[16 + i];

    __shared__ __align__(16) u16 Asl[64 * 64];    //  8 KB: [row][64 u16]
    __shared__ __align__(16) u16 Bsl[128 * 64];   // 16 KB: [col][64 u16]

    int tid = threadIdx.x;
    int wv = tid >> 6, lane = tid & 63;
    int l16 = lane & 15, quad = lane >> 4;
    int wm = wv & 1, wn = wv >> 1;

    // --- staging pointers. lane->lds is uniform-base + lane*16 by construction ---
    int lr = lane >> 3, lc = lane & 7;
    // A: issue0 rows wv*8+lr, issue1 rows +32
    int r0 = wv * 8 + lr, r1 = r0 + 32;
    int tokA0 = tok_list[e * BS + min(t0 + r0, n - 1)];
    int tokA1 = tok_list[e * BS + min(t0 + r1, n - 1)];
    const u16* agp0 = xb + (size_t)tokA0 * H + (size_t)((lc ^ (r0 & 7)) * 8);
    const u16* agp1 = xb + (size_t)tokA1 * H + (size_t)((lc ^ (r1 & 7)) * 8);
    u16* alp0 = &Asl[r0 * 64 + lc * 8];
    u16* alp1 = &Asl[r1 * 64 + lc * 8];
    // B: 4 issues, cols j*32 + wv*8 + lr; cols 0..63 = g (f0+c), 64..127 = u (512+f0+c-64)
    const u16* gb = gup_t + ((size_t)e << 20);
    const u16* bgp[4]; u16* blp[4];
#pragma unroll
    for (int j = 0; j < 4; j++) {
        int c = j * 32 + wv * 8 + lr;
        int gcol = (c < 64) ? (f0 + c) : (512 + f0 + (c - 64));
        bgp[j] = gb + (size_t)gcol * H + (size_t)((lc ^ (c & 7)) * 8);
        blp[j] = &Bsl[c * 64 + lc * 8];
    }

    f32x4 acc[2][4];   // [mi][nj]: nj 0,1 = g frags, 2,3 = u frags
#pragma unroll
    for (int i = 0; i < 2; i++)
#pragma unroll
        for (int j = 0; j < 4; j++) acc[i][j] = (f32x4){0.f, 0.f, 0.f, 0.f};

    int sw = l16 & 7;  // swizzle key for fragment reads (row&7 == col&7 == l16&7)
    for (int k0 = 0; k0 < H; k0 += 64) {
        async_cp16(agp0 + k0, alp0);
        async_cp16(agp1 + k0, alp1);
#pragma unroll
        for (int j = 0; j < 4; j++) async_cp16(bgp[j] + k0, blp[j]);
        __syncthreads();   // drains vmcnt -> LDS ready
#pragma unroll
        for (int s = 0; s < 2; s++) {
            int ch = ((s * 4 + quad) ^ sw) * 8;
            bf16x8 af[2], bfr[4];
#pragma unroll
            for (int i = 0; i < 2; i++)
                af[i] = *(const bf16x8*)&Asl[(wm * 32 + i * 16 + l16) * 64 + ch];
#pragma unroll
            for (int j = 0; j < 4; j++) {
                int col = (j < 2) ? (wn * 32 + j * 16 + l16) : (64 + wn * 32 + (j - 2) * 16 + l16);
                bfr[j] = *(const bf16x8*)&Bsl[col * 64 + ch];
            }
#pragma unroll
            for (int i = 0; i < 2; i++)
#pragma unroll
                for (int j = 0; j < 4; j++)
                    acc[i][j] = __builtin_amdgcn_mfma_f32_16x16x32_bf16(af[i], bfr[j], acc[i][j], 0, 0, 0);
        }
        __syncthreads();   // before next stage overwrites
    }
    // epilogue: C layout col=l16, row=quad*4+reg
#pragma unroll
    for (int i = 0; i < 2; i++)
#pragma unroll
        for (int r = 0; r < 4; r++) {
            int R = t0 + wm * 32 + i * 16 + quad * 4 + r;
            if (R < n) {
                float w = w_list[e * BS + R];
                size_t rowoff = (size_t)(base + R) * F + f0 + wn * 32 + l16;
#pragma unroll
                for (int j = 0; j < 2; j++) {
                    float g = acc[i][j][r], u = acc[i][j + 2][r];
                    float v = (g / (1.f + expf(-g))) * u * w;
                    act[rowoff + j * 16] = f2bf(v);
                }
            }
        }
}

// down MFMA v4: tile M=64, N=128 h-cols, K=F=512, same staging structure.
__global__ __launch_bounds__(256) void down_mfma_kernel(
    const u16* __restrict__ act, const u16* __restrict__ down_t,
    const int* __restrict__ counters, const int* __restrict__ tok_list,
    float* __restrict__ out)
{
    int e = blockIdx.z;
    int n = counters[16 + e];
    int t0 = blockIdx.y * 64;
    if (t0 >= n) return;
    int h0 = blockIdx.x * 128;
    int base = 0;
#pragma unroll
    for (int i = 0; i < E; i++) if (i < e) base += counters[16 + i];

    __shared__ __align__(16) u16 Asl[64 * 64];    //  8 KB
    __shared__ __align__(16) u16 Bsl[128 * 64];   // 16 KB

    int tid = threadIdx.x;
    int wv = tid >> 6, lane = tid & 63;
    int l16 = lane & 15, quad = lane >> 4;
    int wm = wv & 1, wn = wv >> 1;

    int lr = lane >> 3, lc = lane & 7;
    int r0 = wv * 8 + lr, r1 = r0 + 32;
    const u16* agp0 = act + (size_t)(base + min(t0 + r0, n - 1)) * F + (size_t)((lc ^ (r0 & 7)) * 8);
    const u16* agp1 = act + (size_t)(base + min(t0 + r1, n - 1)) * F + (size_t)((lc ^ (r1 & 7)) * 8);
    u16* alp0 = &Asl[r0 * 64 + lc * 8];
    u16* alp1 = &Asl[r1 * 64 + lc * 8];
    const u16* db = down_t + ((size_t)e << 19);
    const u16* bgp[4]; u16* blp[4];
#pragma unroll
    for (int j = 0; j < 4; j++) {
        int c = j * 32 + wv * 8 + lr;
        bgp[j] = db + (size_t)(h0 + c) * F + (size_t)((lc ^ (c & 7)) * 8);
        blp[j] = &Bsl[c * 64 + lc * 8];
    }

    f32x4 acc[2][4];
#pragma unroll
    for (int i = 0; i < 2; i++)
#pragma unroll
        for (int j = 0; j < 4; j++) acc[i][j] = (f32x4){0.f, 0.f, 0.f, 0.f};

    int sw = l16 & 7;
    for (int k0 = 0; k0 < F; k0 += 64) {
        async_cp16(agp0 + k0, alp0);
        async_cp16(agp1 + k0, alp1);
#pragma unroll
        for (int j = 0; j < 4; j++) async_cp16(bgp[j] + k0, blp[j]);
        __syncthreads();
#pragma unroll
        for (int s = 0; s < 2; s++) {
            int ch = ((s * 4 + quad) ^ sw) * 8;
            bf16x8 af[2], bfr[4];
#pragma unroll
            for (int i = 0; i < 2; i++)
                af[i] = *(const bf16x8*)&Asl[(wm * 32 + i * 16 + l16) * 64 + ch];
#pragma unroll
            for (int j = 0; j < 4; j++)
                bfr[j] = *(const bf16x8*)&Bsl[(wn * 64 + j * 16 + l16) * 64 + ch];
#pragma unroll
            for (int i = 0; i < 2; i++)
#pragma unroll
                for (int j = 0; j < 4; j++)
                    acc[i][j] = __builtin_amdgcn_mfma_f32_16x16x32_bf16(af[i], bfr[j], acc[i][j], 0, 0, 0);
        }
        __syncthreads();
    }
#pragma unroll
    for (int i = 0; i < 2; i++)
#pragma unroll
        for (int r = 0; r < 4; r++) {
            int R = t0 + wm * 32 + i * 16 + quad * 4 + r;
            if (R < n) {
                int tok = tok_list[e * BS + R];
                float* orow = out + (size_t)tok * H + h0 + wn * 64 + l16;
#pragma unroll
                for (int j = 0; j < 4; j++)
                    atomicAdd(&orow[j * 16], acc[i][j][r]);
            }
        }
}

extern "C" void kernel_launch(void* const* d_in, const int* in_sizes, int n_in,
                              void* d_out, int out_size, void* d_ws, size_t ws_size,
                              hipStream_t stream)
{
    const float* x       = (const float*)d_in[0];
    const float* gate_w  = (const float*)d_in[1];
    const float* gup     = (const float*)d_in[2];
    const float* down    = (const float*)d_in[3];
    const int*   tok_mod = (const int*)d_in[4];
    const int*   exp_mod = (const int*)d_in[5];
    float* out = (float*)d_out;

    char* ws = (char*)d_ws;
    int*    counters = (int*)ws;
    int2*   sel      = (int2*)(ws + 4096);
    float2* wsel     = (float2*)(ws + 20480);
    int*    tok_list = (int*)(ws + 36864);
    float*  w_list   = (float*)(ws + 102400);
    u16*    x_bf     = (u16*)(ws + 167936);
    u16*    gup_t    = (u16*)(ws + 4362240);
    u16*    down_t   = (u16*)(ws + 21139456);
    u16*    act      = (u16*)(ws + 29528064);

    zero_kernel<<<2048, 256, 0, stream>>>(out, counters);
    transpose_gup_kernel<<<dim3(16, 16, E), 256, 0, stream>>>(gup, gup_t);
    transpose_down_kernel<<<dim3(8, 16, E), 256, 0, stream>>>(down, down_t);
    router_kernel<<<BS / 4, 256, 0, stream>>>(x, gate_w, tok_mod, exp_mod, counters, sel, wsel, x_bf);
    finalize_kernel<<<BS / 256, 256, 0, stream>>>(exp_mod, counters, sel, wsel, tok_list, w_list);
    gu_mfma_kernel<<<dim3(8, 32, E), 256, 0, stream>>>(x_bf, gup_t, counters, tok_list, w_list, act);
    down_mfma_kernel<<<dim3(8, 32, E), 256, 0, stream>>>(act, down_t, counters, tok_list, out);
}

// Round 5
// 185.805 us; speedup vs baseline: 1.3642x; 1.0595x over previous
//
#include <hip/hip_runtime.h>
#include <math.h>

#define BS 2048   // B*S tokens
#define H  1024
#define E  8
#define F  512

typedef __attribute__((ext_vector_type(8))) short bf16x8;
typedef __attribute__((ext_vector_type(4))) float f32x4;
typedef unsigned short u16;
typedef unsigned int u32;

__device__ inline u16 f2bf(float f) {
    u32 u = __float_as_uint(f);
    return (u16)((u + 0x7fffu + ((u >> 16) & 1u)) >> 16);
}

// async 16B global->LDS. LDS dst is wave-uniform base + lane*16 by construction.
__device__ __forceinline__ void async_cp16(const u16* g, u16* l) {
    __builtin_amdgcn_global_load_lds(
        (const __attribute__((address_space(1))) void*)g,
        (__attribute__((address_space(3))) void*)l, 16, 0, 0);
}

// ws layout (bytes):
//        0: counters: valid[8], mismatch[8], gcount[8]
//     4096: sel      int2[BS]
//    20480: wsel     float2[BS]
//    36864: tok_list int[E*BS]
//   102400: w_list   float[E*BS]
//   167936: x_bf     u16[BS*H]            (4 MB)
//  4362240: gup_t    u16[E*1024*1024]     (16 MB)  [e][f-col][h-k] transposed bf16
// 21139456: down_t   u16[E*1024*512]      (8 MB)   [e][h-col][f-k] transposed bf16
// 29528064: act      u16[4096*F]          (4 MB)   w-scaled silu(g)*u, bf16

// ---- prep: both weight transposes (fp32 [k][n] -> bf16 [n][k]) + counter zero ----
__global__ __launch_bounds__(256) void prep_weights_kernel(
    const float* __restrict__ g, const float* __restrict__ d,
    u16* __restrict__ gt, u16* __restrict__ dt, int* __restrict__ counters)
{
    int b = blockIdx.x;
    int tid = threadIdx.x;
    if (b == 0 && tid < 24) counters[tid] = 0;

    const float* src; u16* dst_base; int e, kt, nt, K, Nn;
    if (b < 2048) {           // gup: e in [0,8), 16 k-tiles x 16 n-tiles
        e = b >> 8; int rem = b & 255; kt = rem >> 4; nt = rem & 15;
        src = g + (size_t)e * 1048576; dst_base = gt + (size_t)e * 1048576; K = 1024; Nn = 1024;
    } else {                  // down: e in [0,8), 8 k-tiles x 16 n-tiles
        int b2 = b - 2048; e = b2 >> 7; int rem = b2 & 127; kt = rem >> 4; nt = rem & 15;
        src = d + (size_t)e * 524288; dst_base = dt + (size_t)e * 524288; K = 512; Nn = 1024;
    }
    int k0 = kt * 64, n0 = nt * 64;
    __shared__ float t[64][68];
    int r = tid >> 2, c4 = tid & 3;
    const float* srow = src + (size_t)(k0 + r) * Nn + n0 + c4 * 16;
#pragma unroll
    for (int i = 0; i < 4; i++) {
        float4 v = *(const float4*)(srow + i * 4);
        *(float4*)&t[r][c4 * 16 + i * 4] = v;
    }
    __syncthreads();
    u16 o[16];
#pragma unroll
    for (int m = 0; m < 16; m++) o[m] = f2bf(t[c4 * 16 + m][r]);
    u16* dst = dst_base + (size_t)(n0 + r) * K + k0 + c4 * 16;
    uint4 q0, q1;
    q0.x = (u32)o[0] | ((u32)o[1] << 16);  q0.y = (u32)o[2] | ((u32)o[3] << 16);
    q0.z = (u32)o[4] | ((u32)o[5] << 16);  q0.w = (u32)o[6] | ((u32)o[7] << 16);
    q1.x = (u32)o[8] | ((u32)o[9] << 16);  q1.y = (u32)o[10] | ((u32)o[11] << 16);
    q1.z = (u32)o[12] | ((u32)o[13] << 16); q1.w = (u32)o[14] | ((u32)o[15] << 16);
    *(uint4*)dst = q0;
    *(uint4*)(dst + 8) = q1;
}

// router + x->bf16 conversion + out-row zeroing. One wave per token.
__global__ __launch_bounds__(256) void router_kernel(
    const float* __restrict__ x, const float* __restrict__ gate_w,
    const int* __restrict__ tok_mod, const int* __restrict__ exp_mod,
    int* __restrict__ counters, int2* __restrict__ sel_out, float2* __restrict__ w_out,
    u16* __restrict__ xb, float* __restrict__ out)
{
    int tid = threadIdx.x;
    int wv = tid >> 6, lane = tid & 63;
    int token = blockIdx.x * 4 + wv;    // grid = BS/4 = 512
    // zero this token's output row (harness poisons d_out)
    float4 z = make_float4(0.f, 0.f, 0.f, 0.f);
    float4* orow4 = (float4*)(out + (size_t)token * H);
#pragma unroll
    for (int i = 0; i < 4; i++) orow4[lane + 64 * i] = z;

    const float4* xr4 = (const float4*)(x + (size_t)token * H);
    const float4* gw4 = (const float4*)gate_w;
    float acc[E];
#pragma unroll
    for (int e = 0; e < E; e++) acc[e] = 0.f;
#pragma unroll
    for (int i = 0; i < 4; i++) {
        int idx = lane + 64 * i;
        float4 xv = xr4[idx];
        ushort4 pk;
        pk.x = f2bf(xv.x); pk.y = f2bf(xv.y); pk.z = f2bf(xv.z); pk.w = f2bf(xv.w);
        *(ushort4*)(xb + (size_t)token * H + idx * 4) = pk;
#pragma unroll
        for (int e = 0; e < E; e++) {
            float4 g = gw4[e * 256 + idx];
            acc[e] += xv.x * g.x + xv.y * g.y + xv.z * g.z + xv.w * g.w;
        }
    }
#pragma unroll
    for (int e = 0; e < E; e++) {
#pragma unroll
        for (int off = 32; off > 0; off >>= 1) acc[e] += __shfl_down(acc[e], off, 64);
    }
    if (lane == 0) {
        float m = acc[0];
#pragma unroll
        for (int e = 1; e < E; e++) m = fmaxf(m, acc[e]);
        float p[E]; float s = 0.f;
#pragma unroll
        for (int e = 0; e < E; e++) { p[e] = expf(acc[e] - m); s += p[e]; }
        float inv = 1.f / s;
#pragma unroll
        for (int e = 0; e < E; e++) p[e] *= inv;
        int i0 = 0; float p0 = p[0];
#pragma unroll
        for (int e = 1; e < E; e++) if (p[e] > p0) { p0 = p[e]; i0 = e; }
        int i1 = -1; float p1 = -1.f;
#pragma unroll
        for (int e = 0; e < E; e++) if (e != i0 && p[e] > p1) { p1 = p[e]; i1 = e; }
        float rs = 1.f / (p0 + p1);
        float w0 = p0 * rs, w1 = p1 * rs;
        int tm = tok_mod[token];
        int em0 = exp_mod[i0], em1 = exp_mod[i1];
        bool v0 = (tm != 0) && (em0 != 0);
        bool v1 = (tm != 0) && (em1 != 0);
        bool mm0 = v0 && (tm * em0 == -1);
        bool mm1 = v1 && (tm * em1 == -1);
        if (v0)  atomicAdd(&counters[i0], 1);
        if (v1)  atomicAdd(&counters[i1], 1);
        if (mm0) atomicAdd(&counters[8 + i0], 1);
        if (mm1) atomicAdd(&counters[8 + i1], 1);
        sel_out[token] = make_int2(i0, i1);
        w_out[token] = make_float2(w0, w1);
    }
}

__global__ __launch_bounds__(256) void finalize_kernel(
    const int* __restrict__ exp_mod, int* __restrict__ counters,
    const int2* __restrict__ sel_in, const float2* __restrict__ w_in,
    int* __restrict__ tok_list, float* __restrict__ w_list)
{
    int t = blockIdx.x * 256 + threadIdx.x;
    if (t >= BS) return;
    bool skip[E];
#pragma unroll
    for (int e = 0; e < E; e++) {
        int vc = counters[e], mc = counters[8 + e];
        skip[e] = (vc > 0) && (mc == vc) && (exp_mod[e] != 0);
    }
    int2 sel = sel_in[t];
    float2 w = w_in[t];
    float w0 = skip[sel.x] ? 0.f : w.x;
    float w1 = skip[sel.y] ? 0.f : w.y;
    float s = w0 + w1;
    if (s > 0.f) { float inv = 1.f / fmaxf(s, 1e-9f); w0 *= inv; w1 *= inv; }
    if (w0 > 0.f) {
        int pos = atomicAdd(&counters[16 + sel.x], 1);
        tok_list[sel.x * BS + pos] = t; w_list[sel.x * BS + pos] = w0;
    }
    if (w1 > 0.f) {
        int pos = atomicAdd(&counters[16 + sel.y], 1);
        tok_list[sel.y * BS + pos] = t; w_list[sel.y * BS + pos] = w1;
    }
}

// gu MFMA v5: tile M=64, N=128 (g64|u64), BK=64, XOR-swizzled LDS, dbuf + 1 barrier/kstep.
__global__ __launch_bounds__(256) void gu_mfma_kernel(
    const u16* __restrict__ xb, const u16* __restrict__ gup_t,
    const int* __restrict__ counters, const int* __restrict__ tok_list,
    const float* __restrict__ w_list, u16* __restrict__ act)
{
    int e = blockIdx.z;
    int n = counters[16 + e];
    int t0 = blockIdx.y * 64;
    if (t0 >= n) return;
    int f0 = blockIdx.x * 64;
    int base = 0;
#pragma unroll
    for (int i = 0; i < E; i++) if (i < e) base += counters[16 + i];

    __shared__ __align__(16) u16 Asl[2][64 * 64];    // 2 x  8 KB
    __shared__ __align__(16) u16 Bsl[2][128 * 64];   // 2 x 16 KB

    int tid = threadIdx.x;
    int wv = tid >> 6, lane = tid & 63;
    int l16 = lane & 15, quad = lane >> 4;
    int wm = wv & 1, wn = wv >> 1;

    int lr = lane >> 3, lc = lane & 7;
    int r0 = wv * 8 + lr, r1 = r0 + 32;
    int tokA0 = tok_list[e * BS + min(t0 + r0, n - 1)];
    int tokA1 = tok_list[e * BS + min(t0 + r1, n - 1)];
    const u16* agp0 = xb + (size_t)tokA0 * H + (size_t)((lc ^ (r0 & 7)) * 8);
    const u16* agp1 = xb + (size_t)tokA1 * H + (size_t)((lc ^ (r1 & 7)) * 8);
    int alo0 = r0 * 64 + lc * 8, alo1 = r1 * 64 + lc * 8;
    const u16* gb = gup_t + ((size_t)e << 20);
    const u16* bgp[4]; int blo[4];
#pragma unroll
    for (int j = 0; j < 4; j++) {
        int c = j * 32 + wv * 8 + lr;
        int gcol = (c < 64) ? (f0 + c) : (512 + f0 + (c - 64));
        bgp[j] = gb + (size_t)gcol * H + (size_t)((lc ^ (c & 7)) * 8);
        blo[j] = c * 64 + lc * 8;
    }

    f32x4 acc[2][4];   // [mi][nj]: nj 0,1 = g frags, 2,3 = u frags
#pragma unroll
    for (int i = 0; i < 2; i++)
#pragma unroll
        for (int j = 0; j < 4; j++) acc[i][j] = (f32x4){0.f, 0.f, 0.f, 0.f};

    // prologue: stage k=0 into buf 0
    async_cp16(agp0, &Asl[0][alo0]);
    async_cp16(agp1, &Asl[0][alo1]);
#pragma unroll
    for (int j = 0; j < 4; j++) async_cp16(bgp[j], &Bsl[0][blo[j]]);

    int sw = l16 & 7;
    int p = 0;
    for (int k0 = 0; k0 < H; k0 += 64) {
        __syncthreads();   // drains in-flight global_load_lds -> buf p ready
        if (k0 + 64 < H) { // prefetch next k-step into buf p^1 (overlaps MFMA below)
            int q = p ^ 1;
            async_cp16(agp0 + k0 + 64, &Asl[q][alo0]);
            async_cp16(agp1 + k0 + 64, &Asl[q][alo1]);
#pragma unroll
            for (int j = 0; j < 4; j++) async_cp16(bgp[j] + k0 + 64, &Bsl[q][blo[j]]);
        }
#pragma unroll
        for (int s = 0; s < 2; s++) {
            int ch = ((s * 4 + quad) ^ sw) * 8;
            bf16x8 af[2], bfr[4];
#pragma unroll
            for (int i = 0; i < 2; i++)
                af[i] = *(const bf16x8*)&Asl[p][(wm * 32 + i * 16 + l16) * 64 + ch];
#pragma unroll
            for (int j = 0; j < 4; j++) {
                int col = (j < 2) ? (wn * 32 + j * 16 + l16) : (64 + wn * 32 + (j - 2) * 16 + l16);
                bfr[j] = *(const bf16x8*)&Bsl[p][col * 64 + ch];
            }
#pragma unroll
            for (int i = 0; i < 2; i++)
#pragma unroll
                for (int j = 0; j < 4; j++)
                    acc[i][j] = __builtin_amdgcn_mfma_f32_16x16x32_bf16(af[i], bfr[j], acc[i][j], 0, 0, 0);
        }
        p ^= 1;
    }
    // epilogue: C layout col=l16, row=quad*4+reg
#pragma unroll
    for (int i = 0; i < 2; i++)
#pragma unroll
        for (int r = 0; r < 4; r++) {
            int R = t0 + wm * 32 + i * 16 + quad * 4 + r;
            if (R < n) {
                float w = w_list[e * BS + R];
                size_t rowoff = (size_t)(base + R) * F + f0 + wn * 32 + l16;
#pragma unroll
                for (int j = 0; j < 2; j++) {
                    float g = acc[i][j][r], u = acc[i][j + 2][r];
                    float v = (g / (1.f + expf(-g))) * u * w;
                    act[rowoff + j * 16] = f2bf(v);
                }
            }
        }
}

// down MFMA v5: tile M=64, N=128 h-cols, K=F=512, same dbuf structure, atomic scatter.
__global__ __launch_bounds__(256) void down_mfma_kernel(
    const u16* __restrict__ act, const u16* __restrict__ down_t,
    const int* __restrict__ counters, const int* __restrict__ tok_list,
    float* __restrict__ out)
{
    int e = blockIdx.z;
    int n = counters[16 + e];
    int t0 = blockIdx.y * 64;
    if (t0 >= n) return;
    int h0 = blockIdx.x * 128;
    int base = 0;
#pragma unroll
    for (int i = 0; i < E; i++) if (i < e) base += counters[16 + i];

    __shared__ __align__(16) u16 Asl[2][64 * 64];
    __shared__ __align__(16) u16 Bsl[2][128 * 64];

    int tid = threadIdx.x;
    int wv = tid >> 6, lane = tid & 63;
    int l16 = lane & 15, quad = lane >> 4;
    int wm = wv & 1, wn = wv >> 1;

    int lr = lane >> 3, lc = lane & 7;
    int r0 = wv * 8 + lr, r1 = r0 + 32;
    const u16* agp0 = act + (size_t)(base + min(t0 + r0, n - 1)) * F + (size_t)((lc ^ (r0 & 7)) * 8);
    const u16* agp1 = act + (size_t)(base + min(t0 + r1, n - 1)) * F + (size_t)((lc ^ (r1 & 7)) * 8);
    int alo0 = r0 * 64 + lc * 8, alo1 = r1 * 64 + lc * 8;
    const u16* db = down_t + ((size_t)e << 19);
    const u16* bgp[4]; int blo[4];
#pragma unroll
    for (int j = 0; j < 4; j++) {
        int c = j * 32 + wv * 8 + lr;
        bgp[j] = db + (size_t)(h0 + c) * F + (size_t)((lc ^ (c & 7)) * 8);
        blo[j] = c * 64 + lc * 8;
    }

    f32x4 acc[2][4];
#pragma unroll
    for (int i = 0; i < 2; i++)
#pragma unroll
        for (int j = 0; j < 4; j++) acc[i][j] = (f32x4){0.f, 0.f, 0.f, 0.f};

    async_cp16(agp0, &Asl[0][alo0]);
    async_cp16(agp1, &Asl[0][alo1]);
#pragma unroll
    for (int j = 0; j < 4; j++) async_cp16(bgp[j], &Bsl[0][blo[j]]);

    int sw = l16 & 7;
    int p = 0;
    for (int k0 = 0; k0 < F; k0 += 64) {
        __syncthreads();
        if (k0 + 64 < F) {
            int q = p ^ 1;
            async_cp16(agp0 + k0 + 64, &Asl[q][alo0]);
            async_cp16(agp1 + k0 + 64, &Asl[q][alo1]);
#pragma unroll
            for (int j = 0; j < 4; j++) async_cp16(bgp[j] + k0 + 64, &Bsl[q][blo[j]]);
        }
#pragma unroll
        for (int s = 0; s < 2; s++) {
            int ch = ((s * 4 + quad) ^ sw) * 8;
            bf16x8 af[2], bfr[4];
#pragma unroll
            for (int i = 0; i < 2; i++)
                af[i] = *(const bf16x8*)&Asl[p][(wm * 32 + i * 16 + l16) * 64 + ch];
#pragma unroll
            for (int j = 0; j < 4; j++)
                bfr[j] = *(const bf16x8*)&Bsl[p][(wn * 64 + j * 16 + l16) * 64 + ch];
#pragma unroll
            for (int i = 0; i < 2; i++)
#pragma unroll
                for (int j = 0; j < 4; j++)
                    acc[i][j] = __builtin_amdgcn_mfma_f32_16x16x32_bf16(af[i], bfr[j], acc[i][j], 0, 0, 0);
        }
        p ^= 1;
    }
#pragma unroll
    for (int i = 0; i < 2; i++)
#pragma unroll
        for (int r = 0; r < 4; r++) {
            int R = t0 + wm * 32 + i * 16 + quad * 4 + r;
            if (R < n) {
                int tok = tok_list[e * BS + R];
                float* orow = out + (size_t)tok * H + h0 + wn * 64 + l16;
#pragma unroll
                for (int j = 0; j < 4; j++)
                    atomicAdd(&orow[j * 16], acc[i][j][r]);
            }
        }
}

extern "C" void kernel_launch(void* const* d_in, const int* in_sizes, int n_in,
                              void* d_out, int out_size, void* d_ws, size_t ws_size,
                              hipStream_t stream)
{
    const float* x       = (const float*)d_in[0];
    const float* gate_w  = (const float*)d_in[1];
    const float* gup     = (const float*)d_in[2];
    const float* down    = (const float*)d_in[3];
    const int*   tok_mod = (const int*)d_in[4];
    const int*   exp_mod = (const int*)d_in[5];
    float* out = (float*)d_out;

    char* ws = (char*)d_ws;
    int*    counters = (int*)ws;
    int2*   sel      = (int2*)(ws + 4096);
    float2* wsel     = (float2*)(ws + 20480);
    int*    tok_list = (int*)(ws + 36864);
    float*  w_list   = (float*)(ws + 102400);
    u16*    x_bf     = (u16*)(ws + 167936);
    u16*    gup_t    = (u16*)(ws + 4362240);
    u16*    down_t   = (u16*)(ws + 21139456);
    u16*    act      = (u16*)(ws + 29528064);

    prep_weights_kernel<<<3072, 256, 0, stream>>>(gup, down, gup_t, down_t, counters);
    router_kernel<<<BS / 4, 256, 0, stream>>>(x, gate_w, tok_mod, exp_mod, counters, sel, wsel, x_bf, out);
    finalize_kernel<<<BS / 256, 256, 0, stream>>>(exp_mod, counters, sel, wsel, tok_list, w_list);
    gu_mfma_kernel<<<dim3(8, 32, E), 256, 0, stream>>>(x_bf, gup_t, counters, tok_list, w_list, act);
    down_mfma_kernel<<<dim3(8, 32, E), 256, 0, stream>>>(act, down_t, counters, tok_list, out);
}

// Round 6
// 157.268 us; speedup vs baseline: 1.6117x; 1.1815x over previous
//
#include <hip/hip_runtime.h>
#include <math.h>

#define BS 2048   // B*S tokens
#define H  1024
#define E  8
#define F  512

typedef __attribute__((ext_vector_type(8))) short bf16x8;
typedef __attribute__((ext_vector_type(4))) float f32x4;
typedef unsigned short u16;
typedef unsigned int u32;

__device__ inline u16 f2bf(float f) {
    u32 u = __float_as_uint(f);
    return (u16)((u + 0x7fffu + ((u >> 16) & 1u)) >> 16);
}

// async 16B global->LDS. LDS dst is wave-uniform base + lane*16 by construction.
__device__ __forceinline__ void async_cp16(const u16* g, u16* l) {
    __builtin_amdgcn_global_load_lds(
        (const __attribute__((address_space(1))) void*)g,
        (__attribute__((address_space(3))) void*)l, 16, 0, 0);
}

// ws layout (bytes):
//        0: counters: [16..24) = per-expert gathered counts
//     4096: sel      int2[BS]   (expert id | valid<<8 | mismatch<<9 per slot)
//    20480: wsel     float2[BS]
//    36864: tok_list int[E*BS]
//   102400: w_list   float[E*BS]
//   167936: x_bf     u16[BS*H]            (4 MB)
//  4362240: gup_t    u16[E*1024*1024]     (16 MB)  [e][f-col][h-k] transposed bf16
// 21139456: down_t   u16[E*1024*512]      (8 MB)   [e][h-col][f-k] transposed bf16
// 29528064: act      u16[4096*F]          (4 MB)   w-scaled silu(g)*u, bf16

// ---- K1: fused weight transpose (blocks 0..3071) + router (blocks 3072..3583) ----
__global__ __launch_bounds__(256) void prep_router_kernel(
    const float* __restrict__ gup, const float* __restrict__ dwn,
    u16* __restrict__ gt, u16* __restrict__ dt,
    const float* __restrict__ x, const float* __restrict__ gate_w,
    const int* __restrict__ tok_mod, const int* __restrict__ exp_mod,
    int2* __restrict__ sel_out, float2* __restrict__ w_out,
    u16* __restrict__ xb, float* __restrict__ out)
{
    int b = blockIdx.x;
    int tid = threadIdx.x;

    if (b < 3072) {
        // ---------- weight transpose: fp32 [k][n] -> bf16 [n][k] ----------
        const float* src; u16* dst_base; int e, kt, nt, K, Nn;
        if (b < 2048) {           // gup: e in [0,8), 16 k-tiles x 16 n-tiles
            e = b >> 8; int rem = b & 255; kt = rem >> 4; nt = rem & 15;
            src = gup + (size_t)e * 1048576; dst_base = gt + (size_t)e * 1048576; K = 1024; Nn = 1024;
        } else {                  // down: e in [0,8), 8 k-tiles x 16 n-tiles
            int b2 = b - 2048; e = b2 >> 7; int rem = b2 & 127; kt = rem >> 4; nt = rem & 15;
            src = dwn + (size_t)e * 524288; dst_base = dt + (size_t)e * 524288; K = 512; Nn = 1024;
        }
        int k0 = kt * 64, n0 = nt * 64;
        __shared__ float t[64][68];
        int r = tid >> 2, c4 = tid & 3;
        const float* srow = src + (size_t)(k0 + r) * Nn + n0 + c4 * 16;
#pragma unroll
        for (int i = 0; i < 4; i++) {
            float4 v = *(const float4*)(srow + i * 4);
            *(float4*)&t[r][c4 * 16 + i * 4] = v;
        }
        __syncthreads();
        u16 o[16];
#pragma unroll
        for (int m = 0; m < 16; m++) o[m] = f2bf(t[c4 * 16 + m][r]);
        u16* dst = dst_base + (size_t)(n0 + r) * K + k0 + c4 * 16;
        uint4 q0, q1;
        q0.x = (u32)o[0] | ((u32)o[1] << 16);  q0.y = (u32)o[2] | ((u32)o[3] << 16);
        q0.z = (u32)o[4] | ((u32)o[5] << 16);  q0.w = (u32)o[6] | ((u32)o[7] << 16);
        q1.x = (u32)o[8] | ((u32)o[9] << 16);  q1.y = (u32)o[10] | ((u32)o[11] << 16);
        q1.z = (u32)o[12] | ((u32)o[13] << 16); q1.w = (u32)o[14] | ((u32)o[15] << 16);
        *(uint4*)dst = q0;
        *(uint4*)(dst + 8) = q1;
        return;
    }

    // ---------- router: one wave per token, 4 tokens per block ----------
    int wv = tid >> 6, lane = tid & 63;
    int token = (b - 3072) * 4 + wv;
    // zero this token's output row (harness poisons d_out)
    float4 z = make_float4(0.f, 0.f, 0.f, 0.f);
    float4* orow4 = (float4*)(out + (size_t)token * H);
#pragma unroll
    for (int i = 0; i < 4; i++) orow4[lane + 64 * i] = z;

    const float4* xr4 = (const float4*)(x + (size_t)token * H);
    const float4* gw4 = (const float4*)gate_w;
    float acc[E];
#pragma unroll
    for (int e = 0; e < E; e++) acc[e] = 0.f;
#pragma unroll
    for (int i = 0; i < 4; i++) {
        int idx = lane + 64 * i;
        float4 xv = xr4[idx];
        ushort4 pk;
        pk.x = f2bf(xv.x); pk.y = f2bf(xv.y); pk.z = f2bf(xv.z); pk.w = f2bf(xv.w);
        *(ushort4*)(xb + (size_t)token * H + idx * 4) = pk;
#pragma unroll
        for (int e = 0; e < E; e++) {
            float4 g = gw4[e * 256 + idx];
            acc[e] += xv.x * g.x + xv.y * g.y + xv.z * g.z + xv.w * g.w;
        }
    }
#pragma unroll
    for (int e = 0; e < E; e++) {
#pragma unroll
        for (int off = 32; off > 0; off >>= 1) acc[e] += __shfl_down(acc[e], off, 64);
    }
    if (lane == 0) {
        float m = acc[0];
#pragma unroll
        for (int e = 1; e < E; e++) m = fmaxf(m, acc[e]);
        float p[E]; float s = 0.f;
#pragma unroll
        for (int e = 0; e < E; e++) { p[e] = expf(acc[e] - m); s += p[e]; }
        float inv = 1.f / s;
#pragma unroll
        for (int e = 0; e < E; e++) p[e] *= inv;
        int i0 = 0; float p0 = p[0];
#pragma unroll
        for (int e = 1; e < E; e++) if (p[e] > p0) { p0 = p[e]; i0 = e; }
        int i1 = -1; float p1 = -1.f;
#pragma unroll
        for (int e = 0; e < E; e++) if (e != i0 && p[e] > p1) { p1 = p[e]; i1 = e; }
        float rs = 1.f / (p0 + p1);
        float w0 = p0 * rs, w1 = p1 * rs;
        int tm = tok_mod[token];
        int em0 = exp_mod[i0], em1 = exp_mod[i1];
        int v0 = (tm != 0) && (em0 != 0);
        int v1 = (tm != 0) && (em1 != 0);
        int mm0 = v0 && (tm * em0 == -1);
        int mm1 = v1 && (tm * em1 == -1);
        sel_out[token] = make_int2(i0 | (v0 << 8) | (mm0 << 9),
                                   i1 | (v1 << 8) | (mm1 << 9));
        w_out[token] = make_float2(w0, w1);
    }
}

// ---- K2: single-block finalize: reduce valid/mismatch, skip, renorm, gather ----
__global__ __launch_bounds__(1024) void finalize_kernel(
    const int* __restrict__ exp_mod, int* __restrict__ counters,
    const int2* __restrict__ sel_in, const float2* __restrict__ w_in,
    int* __restrict__ tok_list, float* __restrict__ w_list)
{
    __shared__ int vcnt[E], mcnt[E], gpos[E];
    int tid = threadIdx.x;
    if (tid < E) { vcnt[tid] = 0; mcnt[tid] = 0; gpos[tid] = 0; }
    __syncthreads();
#pragma unroll
    for (int h = 0; h < 2; h++) {
        int t = tid + h * 1024;
        int2 s = sel_in[t];
        int i0 = s.x & 7, i1 = s.y & 7;
        if (s.x & 256) atomicAdd(&vcnt[i0], 1);
        if (s.x & 512) atomicAdd(&mcnt[i0], 1);
        if (s.y & 256) atomicAdd(&vcnt[i1], 1);
        if (s.y & 512) atomicAdd(&mcnt[i1], 1);
    }
    __syncthreads();
    bool skip[E];
#pragma unroll
    for (int e = 0; e < E; e++)
        skip[e] = (vcnt[e] > 0) && (mcnt[e] == vcnt[e]) && (exp_mod[e] != 0);
#pragma unroll
    for (int h = 0; h < 2; h++) {
        int t = tid + h * 1024;
        int2 s = sel_in[t];
        int i0 = s.x & 7, i1 = s.y & 7;
        float2 w = w_in[t];
        float w0 = skip[i0] ? 0.f : w.x;
        float w1 = skip[i1] ? 0.f : w.y;
        float sm = w0 + w1;
        if (sm > 0.f) { float inv = 1.f / fmaxf(sm, 1e-9f); w0 *= inv; w1 *= inv; }
        if (w0 > 0.f) {
            int pos = atomicAdd(&gpos[i0], 1);
            tok_list[i0 * BS + pos] = t; w_list[i0 * BS + pos] = w0;
        }
        if (w1 > 0.f) {
            int pos = atomicAdd(&gpos[i1], 1);
            tok_list[i1 * BS + pos] = t; w_list[i1 * BS + pos] = w1;
        }
    }
    __syncthreads();
    if (tid < E) counters[16 + tid] = gpos[tid];
}

// gu MFMA: tile M=64, N=128 (g64|u64), BK=64, XOR-swizzled LDS, dbuf + 1 barrier/kstep.
__global__ __launch_bounds__(256) void gu_mfma_kernel(
    const u16* __restrict__ xb, const u16* __restrict__ gup_t,
    const int* __restrict__ counters, const int* __restrict__ tok_list,
    const float* __restrict__ w_list, u16* __restrict__ act)
{
    int e = blockIdx.z;
    int n = counters[16 + e];
    int t0 = blockIdx.y * 64;
    if (t0 >= n) return;
    int f0 = blockIdx.x * 64;
    int base = 0;
#pragma unroll
    for (int i = 0; i < E; i++) if (i < e) base += counters[16 + i];

    __shared__ __align__(16) u16 Asl[2][64 * 64];    // 2 x  8 KB
    __shared__ __align__(16) u16 Bsl[2][128 * 64];   // 2 x 16 KB

    int tid = threadIdx.x;
    int wv = tid >> 6, lane = tid & 63;
    int l16 = lane & 15, quad = lane >> 4;
    int wm = wv & 1, wn = wv >> 1;

    int lr = lane >> 3, lc = lane & 7;
    int r0 = wv * 8 + lr, r1 = r0 + 32;
    int tokA0 = tok_list[e * BS + min(t0 + r0, n - 1)];
    int tokA1 = tok_list[e * BS + min(t0 + r1, n - 1)];
    const u16* agp0 = xb + (size_t)tokA0 * H + (size_t)((lc ^ (r0 & 7)) * 8);
    const u16* agp1 = xb + (size_t)tokA1 * H + (size_t)((lc ^ (r1 & 7)) * 8);
    int alo0 = r0 * 64 + lc * 8, alo1 = r1 * 64 + lc * 8;
    const u16* gb = gup_t + ((size_t)e << 20);
    const u16* bgp[4]; int blo[4];
#pragma unroll
    for (int j = 0; j < 4; j++) {
        int c = j * 32 + wv * 8 + lr;
        int gcol = (c < 64) ? (f0 + c) : (512 + f0 + (c - 64));
        bgp[j] = gb + (size_t)gcol * H + (size_t)((lc ^ (c & 7)) * 8);
        blo[j] = c * 64 + lc * 8;
    }

    f32x4 acc[2][4];   // [mi][nj]: nj 0,1 = g frags, 2,3 = u frags
#pragma unroll
    for (int i = 0; i < 2; i++)
#pragma unroll
        for (int j = 0; j < 4; j++) acc[i][j] = (f32x4){0.f, 0.f, 0.f, 0.f};

    // prologue: stage k=0 into buf 0
    async_cp16(agp0, &Asl[0][alo0]);
    async_cp16(agp1, &Asl[0][alo1]);
#pragma unroll
    for (int j = 0; j < 4; j++) async_cp16(bgp[j], &Bsl[0][blo[j]]);

    int sw = l16 & 7;
    int p = 0;
    for (int k0 = 0; k0 < H; k0 += 64) {
        __syncthreads();   // drains in-flight global_load_lds -> buf p ready
        if (k0 + 64 < H) { // prefetch next k-step into buf p^1 (overlaps MFMA below)
            int q = p ^ 1;
            async_cp16(agp0 + k0 + 64, &Asl[q][alo0]);
            async_cp16(agp1 + k0 + 64, &Asl[q][alo1]);
#pragma unroll
            for (int j = 0; j < 4; j++) async_cp16(bgp[j] + k0 + 64, &Bsl[q][blo[j]]);
        }
#pragma unroll
        for (int s = 0; s < 2; s++) {
            int ch = ((s * 4 + quad) ^ sw) * 8;
            bf16x8 af[2], bfr[4];
#pragma unroll
            for (int i = 0; i < 2; i++)
                af[i] = *(const bf16x8*)&Asl[p][(wm * 32 + i * 16 + l16) * 64 + ch];
#pragma unroll
            for (int j = 0; j < 4; j++) {
                int col = (j < 2) ? (wn * 32 + j * 16 + l16) : (64 + wn * 32 + (j - 2) * 16 + l16);
                bfr[j] = *(const bf16x8*)&Bsl[p][col * 64 + ch];
            }
#pragma unroll
            for (int i = 0; i < 2; i++)
#pragma unroll
                for (int j = 0; j < 4; j++)
                    acc[i][j] = __builtin_amdgcn_mfma_f32_16x16x32_bf16(af[i], bfr[j], acc[i][j], 0, 0, 0);
        }
        p ^= 1;
    }
    // epilogue: C layout col=l16, row=quad*4+reg
#pragma unroll
    for (int i = 0; i < 2; i++)
#pragma unroll
        for (int r = 0; r < 4; r++) {
            int R = t0 + wm * 32 + i * 16 + quad * 4 + r;
            if (R < n) {
                float w = w_list[e * BS + R];
                size_t rowoff = (size_t)(base + R) * F + f0 + wn * 32 + l16;
#pragma unroll
                for (int j = 0; j < 2; j++) {
                    float g = acc[i][j][r], u = acc[i][j + 2][r];
                    float v = (g / (1.f + expf(-g))) * u * w;
                    act[rowoff + j * 16] = f2bf(v);
                }
            }
        }
}

// down MFMA: tile M=64, N=128 h-cols, K=F=512, same dbuf structure, atomic scatter.
__global__ __launch_bounds__(256) void down_mfma_kernel(
    const u16* __restrict__ act, const u16* __restrict__ down_t,
    const int* __restrict__ counters, const int* __restrict__ tok_list,
    float* __restrict__ out)
{
    int e = blockIdx.z;
    int n = counters[16 + e];
    int t0 = blockIdx.y * 64;
    if (t0 >= n) return;
    int h0 = blockIdx.x * 128;
    int base = 0;
#pragma unroll
    for (int i = 0; i < E; i++) if (i < e) base += counters[16 + i];

    __shared__ __align__(16) u16 Asl[2][64 * 64];
    __shared__ __align__(16) u16 Bsl[2][128 * 64];

    int tid = threadIdx.x;
    int wv = tid >> 6, lane = tid & 63;
    int l16 = lane & 15, quad = lane >> 4;
    int wm = wv & 1, wn = wv >> 1;

    int lr = lane >> 3, lc = lane & 7;
    int r0 = wv * 8 + lr, r1 = r0 + 32;
    const u16* agp0 = act + (size_t)(base + min(t0 + r0, n - 1)) * F + (size_t)((lc ^ (r0 & 7)) * 8);
    const u16* agp1 = act + (size_t)(base + min(t0 + r1, n - 1)) * F + (size_t)((lc ^ (r1 & 7)) * 8);
    int alo0 = r0 * 64 + lc * 8, alo1 = r1 * 64 + lc * 8;
    const u16* db = down_t + ((size_t)e << 19);
    const u16* bgp[4]; int blo[4];
#pragma unroll
    for (int j = 0; j < 4; j++) {
        int c = j * 32 + wv * 8 + lr;
        bgp[j] = db + (size_t)(h0 + c) * F + (size_t)((lc ^ (c & 7)) * 8);
        blo[j] = c * 64 + lc * 8;
    }

    f32x4 acc[2][4];
#pragma unroll
    for (int i = 0; i < 2; i++)
#pragma unroll
        for (int j = 0; j < 4; j++) acc[i][j] = (f32x4){0.f, 0.f, 0.f, 0.f};

    async_cp16(agp0, &Asl[0][alo0]);
    async_cp16(agp1, &Asl[0][alo1]);
#pragma unroll
    for (int j = 0; j < 4; j++) async_cp16(bgp[j], &Bsl[0][blo[j]]);

    int sw = l16 & 7;
    int p = 0;
    for (int k0 = 0; k0 < F; k0 += 64) {
        __syncthreads();
        if (k0 + 64 < F) {
            int q = p ^ 1;
            async_cp16(agp0 + k0 + 64, &Asl[q][alo0]);
            async_cp16(agp1 + k0 + 64, &Asl[q][alo1]);
#pragma unroll
            for (int j = 0; j < 4; j++) async_cp16(bgp[j] + k0 + 64, &Bsl[q][blo[j]]);
        }
#pragma unroll
        for (int s = 0; s < 2; s++) {
            int ch = ((s * 4 + quad) ^ sw) * 8;
            bf16x8 af[2], bfr[4];
#pragma unroll
            for (int i = 0; i < 2; i++)
                af[i] = *(const bf16x8*)&Asl[p][(wm * 32 + i * 16 + l16) * 64 + ch];
#pragma unroll
            for (int j = 0; j < 4; j++)
                bfr[j] = *(const bf16x8*)&Bsl[p][(wn * 64 + j * 16 + l16) * 64 + ch];
#pragma unroll
            for (int i = 0; i < 2; i++)
#pragma unroll
                for (int j = 0; j < 4; j++)
                    acc[i][j] = __builtin_amdgcn_mfma_f32_16x16x32_bf16(af[i], bfr[j], acc[i][j], 0, 0, 0);
        }
        p ^= 1;
    }
#pragma unroll
    for (int i = 0; i < 2; i++)
#pragma unroll
        for (int r = 0; r < 4; r++) {
            int R = t0 + wm * 32 + i * 16 + quad * 4 + r;
            if (R < n) {
                int tok = tok_list[e * BS + R];
                float* orow = out + (size_t)tok * H + h0 + wn * 64 + l16;
#pragma unroll
                for (int j = 0; j < 4; j++)
                    atomicAdd(&orow[j * 16], acc[i][j][r]);
            }
        }
}

extern "C" void kernel_launch(void* const* d_in, const int* in_sizes, int n_in,
                              void* d_out, int out_size, void* d_ws, size_t ws_size,
                              hipStream_t stream)
{
    const float* x       = (const float*)d_in[0];
    const float* gate_w  = (const float*)d_in[1];
    const float* gup     = (const float*)d_in[2];
    const float* down    = (const float*)d_in[3];
    const int*   tok_mod = (const int*)d_in[4];
    const int*   exp_mod = (const int*)d_in[5];
    float* out = (float*)d_out;

    char* ws = (char*)d_ws;
    int*    counters = (int*)ws;
    int2*   sel      = (int2*)(ws + 4096);
    float2* wsel     = (float2*)(ws + 20480);
    int*    tok_list = (int*)(ws + 36864);
    float*  w_list   = (float*)(ws + 102400);
    u16*    x_bf     = (u16*)(ws + 167936);
    u16*    gup_t    = (u16*)(ws + 4362240);
    u16*    down_t   = (u16*)(ws + 21139456);
    u16*    act      = (u16*)(ws + 29528064);

    prep_router_kernel<<<3584, 256, 0, stream>>>(gup, down, gup_t, down_t,
                                                 x, gate_w, tok_mod, exp_mod,
                                                 sel, wsel, x_bf, out);
    finalize_kernel<<<1, 1024, 0, stream>>>(exp_mod, counters, sel, wsel, tok_list, w_list);
    gu_mfma_kernel<<<dim3(8, 32, E), 256, 0, stream>>>(x_bf, gup_t, counters, tok_list, w_list, act);
    down_mfma_kernel<<<dim3(8, 32, E), 256, 0, stream>>>(act, down_t, counters, tok_list, out);
}